// Round 1
// baseline (75.346 us; speedup 1.0000x reference)
//
#include <hip/hip_runtime.h>
#include <hip/hip_bf16.h>

#define NCLS 13
#define HH 120
#define WW 160
#define HWSZ (HH * WW)       // 19200
#define PSAMP 1200           // 19200 / 16
#define SKIP 16
#define CM1 (NCLS - 1)       // 12

// ---------------- workspace layout (bytes) ----------------
// votes:     int   [12][19200]  @ 0          (921600 B)
// plist:     float4[12][1200]   @ 921600     (230400 B)
// cnt:       int   [12]         @ 1152000
// num_label: int   [12]         @ 1152048
// dzsum:     float [12]         @ 1152096
// total ~1.16 MB

// Kernel 1: per class, compact labeled sampled pixels + full-image stats.
__global__ void hough_prep(const int* __restrict__ labels,
                           const int* __restrict__ masks,
                           const float* __restrict__ vp,
                           float4* __restrict__ plist,
                           int* __restrict__ cnt,
                           int* __restrict__ num_label,
                           float* __restrict__ dzsum) {
    const int c = blockIdx.x + 1;     // classes 1..12
    const int tid = threadIdx.x;
    __shared__ int lcnt;
    __shared__ float red_f[256];
    __shared__ int   red_i[256];
    if (tid == 0) lcnt = 0;
    __syncthreads();

    // compact sampled labeled pixels (order irrelevant: votes are a sum)
    for (int p = tid; p < PSAMP; p += 256) {
        const int i = p * SKIP;
        if (labels[i] == c && masks[i] > 0) {
            float dx = vp[(3 * c + 0) * HWSZ + i];
            float dy = vp[(3 * c + 1) * HWSZ + i];
            // dn = sqrt(dx*dx + dy*dy) + 1e-6  (exact IEEE order, no FMA)
            float dn = __fadd_rn(
                __fsqrt_rn(__fadd_rn(__fmul_rn(dx, dx), __fmul_rn(dy, dy))),
                1e-6f);
            float dxn = __fdiv_rn(dx, dn);
            float dyn = __fdiv_rn(dy, dn);
            int pos = atomicAdd(&lcnt, 1);
            plist[(c - 1) * PSAMP + pos] =
                make_float4((float)(i % WW), (float)(i / WW), dxn, dyn);
        }
    }

    // full-image num_label and dz sum
    int   mycnt = 0;
    float mysum = 0.f;
    const float* dzp = vp + (3 * c + 2) * HWSZ;
    for (int i = tid; i < HWSZ; i += 256) {
        if (labels[i] == c && masks[i] > 0) { mycnt++; mysum += dzp[i]; }
    }
    red_i[tid] = mycnt;
    red_f[tid] = mysum;
    __syncthreads();
    for (int s = 128; s > 0; s >>= 1) {
        if (tid < s) { red_i[tid] += red_i[tid + s]; red_f[tid] += red_f[tid + s]; }
        __syncthreads();
    }
    if (tid == 0) {
        cnt[c - 1]       = lcnt;
        num_label[c - 1] = red_i[0];
        dzsum[c - 1]     = red_f[0];
    }
}

// Kernel 2: vote accumulation. One thread per candidate center.
__global__ void hough_vote(const float4* __restrict__ plist,
                           const int* __restrict__ cnt,
                           int* __restrict__ votes) {
    const int c1 = blockIdx.y;                       // 0..11
    const int g  = blockIdx.x * 256 + threadIdx.x;   // 0..19199 (75*256 exact)
    __shared__ float4 s[PSAMP];
    const int n = cnt[c1];
    for (int j = threadIdx.x; j < n; j += 256) s[j] = plist[c1 * PSAMP + j];
    __syncthreads();

    const float xg = (float)(g % WW);
    const float yg = (float)(g / WW);
    int v = 0;
    for (int j = 0; j < n; ++j) {
        float4 e = s[j];
        float ddx = __fsub_rn(xg, e.x);              // exact (small ints)
        float ddy = __fsub_rn(yg, e.y);
        float d2  = __fadd_rn(__fmul_rn(ddx, ddx), __fmul_rn(ddy, ddy)); // exact
        float dist = __fsqrt_rn(d2);
        float t = __fadd_rn(__fmul_rn(ddx, e.z), __fmul_rn(ddy, e.w));   // no FMA
        float cosang = __fdiv_rn(t, fmaxf(dist, 1e-6f));
        v += (cosang > 0.9f && dist > 0.0f) ? 1 : 0;
    }
    votes[c1 * HWSZ + g] = v;
}

// Kernel 3: per class argmax (first index) + emit all outputs.
__global__ void hough_out(const int* __restrict__ votes,
                          const int* __restrict__ cnt,
                          const int* __restrict__ num_label,
                          const float* __restrict__ dzsum,
                          const float* __restrict__ extents,
                          const float* __restrict__ meta,
                          float* __restrict__ out) {
    const int c1 = blockIdx.x;   // 0..11
    const int c  = c1 + 1;
    const int tid = threadIdx.x;
    __shared__ int rv[256], ri[256];

    int bv = -1, bi = 0;
    for (int g = tid; g < HWSZ; g += 256) {
        int v = votes[c1 * HWSZ + g];
        if (v > bv) { bv = v; bi = g; }   // strided ascending -> keeps first
    }
    rv[tid] = bv; ri[tid] = bi;
    __syncthreads();
    for (int s = 128; s > 0; s >>= 1) {
        if (tid < s) {
            if (rv[tid + s] > rv[tid] ||
                (rv[tid + s] == rv[tid] && ri[tid + s] < ri[tid])) {
                rv[tid] = rv[tid + s];
                ri[tid] = ri[tid + s];
            }
        }
        __syncthreads();
    }

    float* top_box    = out;          // 12 x 7
    float* top_pose   = out + 84;     // 12 x 7
    float* top_target = out + 168;    // 12 x 52
    float* top_weight = out + 792;    // 12 x 52
    float* top_domain = out + 1416;   // 12

    // zero target row (harness poisons d_out between replays)
    for (int j = tid; j < 52; j += 256) top_target[c1 * 52 + j] = 0.f;
    if (c1 == 0) {
        for (int j = tid; j < CM1; j += 256) top_domain[j] = 0.f;
    }

    if (tid == 0) {
        const float vmax = (float)rv[0];
        const int best = ri[0];
        const float cx = (float)(best % WW);
        const float cy = (float)(best / WW);
        const int nl = num_label[c1];
        const float msum = fmaxf((float)nl, 1.0f);
        float z = expf(dzsum[c1] / msum);
        z = fmaxf(z, 1e-3f);
        const float fx = meta[0], fy = meta[4], pxc = meta[2], pyc = meta[5];
        const float bw = extents[c * 3 + 0] * fx / z;
        const float bh = extents[c * 3 + 1] * fy / z;
        const float nsamp = fmaxf((float)cnt[c1], 1.0f);
        const bool valid = (vmax >= 10.0f) && (nl >= 500) &&
                           (vmax >= 0.02f * nsamp);

        float* bx = top_box + c1 * 7;
        bx[0] = 0.0f;               // bidx (B=1)
        bx[1] = (float)c;
        bx[2] = cx - bw * 0.5f;
        bx[3] = cy - bh * 0.5f;
        bx[4] = cx + bw * 0.5f;
        bx[5] = cy + bh * 0.5f;
        bx[6] = vmax;

        const float tx = (cx - pxc) * z / fx;
        const float ty = (cy - pyc) * z / fy;
        float* ps = top_pose + c1 * 7;
        ps[0] = 1.f; ps[1] = 0.f; ps[2] = 0.f; ps[3] = 0.f;
        ps[4] = tx;  ps[5] = ty;  ps[6] = z;

        float* wt = top_weight + c1 * 52;
        const float wv = valid ? 1.0f : 0.0f;
        for (int j = 0; j < 52; ++j)
            wt[j] = ((j >> 2) == c) ? wv : 0.0f;
    }
}

extern "C" void kernel_launch(void* const* d_in, const int* in_sizes, int n_in,
                              void* d_out, int out_size, void* d_ws, size_t ws_size,
                              hipStream_t stream) {
    const int*   labels  = (const int*)d_in[0];
    const int*   masks   = (const int*)d_in[1];
    const float* vp      = (const float*)d_in[2];
    const float* extents = (const float*)d_in[3];
    // d_in[4] = poses (unused by the forward pass)
    const float* meta    = (const float*)d_in[5];
    float* out = (float*)d_out;

    char* ws = (char*)d_ws;
    int*    votes     = (int*)(ws + 0);
    float4* plist     = (float4*)(ws + 921600);
    int*    cnt       = (int*)(ws + 1152000);
    int*    num_label = (int*)(ws + 1152048);
    float*  dzsum     = (float*)(ws + 1152096);

    hough_prep<<<dim3(CM1), dim3(256), 0, stream>>>(labels, masks, vp,
                                                    plist, cnt, num_label, dzsum);
    hough_vote<<<dim3(HWSZ / 256, CM1), dim3(256), 0, stream>>>(plist, cnt, votes);
    hough_out<<<dim3(CM1), dim3(256), 0, stream>>>(votes, cnt, num_label, dzsum,
                                                   extents, meta, out);
}

// Round 2
// 42.972 us; speedup vs baseline: 1.7534x; 1.7534x over previous
//
#include <hip/hip_runtime.h>
#include <hip/hip_bf16.h>

#define NCLS 13
#define HH 120
#define WW 160
#define HWSZ (HH * WW)       // 19200
#define PSAMP 1200           // 19200 / 16
#define CM1 (NCLS - 1)       // 12
#define NBLK 75              // HWSZ / 256

// ---------------- workspace layout (bytes) ----------------
// plist:  float4[12][1200] @ 0        (230400 B)
// pcnt:   int   [12][75]   @ 230400   (3600 B)   per-block num_label partials
// pdz:    float [12][75]   @ 234000   (3600 B)   per-block dz-sum partials
// cnt:    int   [12]       @ 237600   (48 B)     sampled-pixel counts (atomic)
// best:   int   [12]       @ 237648   (48 B)     packed argmax keys (atomicMax)
// memset region: [237600, 237696)

// Kernel 1: one thread per pixel. Compaction of labeled sampled pixels +
// per-block per-class (count, dz-sum) partials via deterministic shfl trees.
__global__ void hough_prep(const int* __restrict__ labels,
                           const int* __restrict__ masks,
                           const float* __restrict__ vp,
                           float4* __restrict__ plist,
                           int* __restrict__ cnt,
                           int* __restrict__ pcnt,
                           float* __restrict__ pdz) {
    const int tid = threadIdx.x;
    const int i = blockIdx.x * 256 + tid;          // < 19200 exactly
    const int lab = labels[i];
    const bool valid = (lab > 0) && (masks[i] > 0);
    const int cls = valid ? lab - 1 : -1;
    float dz = 0.f;
    if (valid) dz = vp[(3 * lab + 2) * HWSZ + i];

    // sampled compaction (order in list irrelevant: votes are a sum)
    if (valid && ((i & 15) == 0)) {
        float dx = vp[(3 * lab + 0) * HWSZ + i];
        float dy = vp[(3 * lab + 1) * HWSZ + i];
        float dn = __fadd_rn(
            __fsqrt_rn(__fadd_rn(__fmul_rn(dx, dx), __fmul_rn(dy, dy))), 1e-6f);
        int pos = atomicAdd(&cnt[cls], 1);
        plist[cls * PSAMP + pos] =
            make_float4((float)(i % WW), (float)(i / WW),
                        __fdiv_rn(dx, dn), __fdiv_rn(dy, dn));
    }

    // per-wave per-class reductions (fixed shuffle tree -> deterministic)
    __shared__ float s_dz[4][CM1];
    __shared__ int   s_ct[4][CM1];
    const int w = tid >> 6, lane = tid & 63;
    for (int c1 = 0; c1 < CM1; ++c1) {
        unsigned long long b = __ballot(cls == c1);
        float v = (cls == c1) ? dz : 0.f;
        for (int off = 32; off > 0; off >>= 1) v += __shfl_xor(v, off);
        if (lane == 0) { s_ct[w][c1] = (int)__popcll(b); s_dz[w][c1] = v; }
    }
    __syncthreads();
    if (tid < CM1) {
        int   ct = s_ct[0][tid] + s_ct[1][tid] + s_ct[2][tid] + s_ct[3][tid];
        float d  = ((s_dz[0][tid] + s_dz[1][tid]) + s_dz[2][tid]) + s_dz[3][tid];
        pcnt[tid * NBLK + blockIdx.x] = ct;
        pdz [tid * NBLK + blockIdx.x] = d;
    }
}

// Kernel 2: vote accumulation fused with argmax.
// key = (v << 15) | (19199 - g): integer max is order-independent;
// max v wins, ties -> smallest g (numpy first-index argmax).
__global__ void hough_vote(const float4* __restrict__ plist,
                           const int* __restrict__ cnt,
                           int* __restrict__ best) {
    const int c1 = blockIdx.y;                       // 0..11
    const int g  = blockIdx.x * 256 + threadIdx.x;   // 0..19199
    __shared__ float4 s[PSAMP];
    const int n = cnt[c1];
    for (int j = threadIdx.x; j < n; j += 256) s[j] = plist[c1 * PSAMP + j];
    __syncthreads();

    const float xg = (float)(g % WW);
    const float yg = (float)(g / WW);
    int v = 0;
    for (int j = 0; j < n; ++j) {
        float4 e = s[j];
        float ddx = __fsub_rn(xg, e.x);
        float ddy = __fsub_rn(yg, e.y);
        float d2  = __fadd_rn(__fmul_rn(ddx, ddx), __fmul_rn(ddy, ddy));
        float dist = __fsqrt_rn(d2);
        float t = __fadd_rn(__fmul_rn(ddx, e.z), __fmul_rn(ddy, e.w));
        float cosang = __fdiv_rn(t, fmaxf(dist, 1e-6f));
        v += (cosang > 0.9f && dist > 0.0f) ? 1 : 0;
    }

    int key = (v << 15) | (19199 - g);
    for (int off = 32; off > 0; off >>= 1) {
        int o = __shfl_xor(key, off);
        key = key > o ? key : o;
    }
    __shared__ int wmax[4];
    if ((threadIdx.x & 63) == 0) wmax[threadIdx.x >> 6] = key;
    __syncthreads();
    if (threadIdx.x == 0) {
        int k01 = wmax[0] > wmax[1] ? wmax[0] : wmax[1];
        int k23 = wmax[2] > wmax[3] ? wmax[2] : wmax[3];
        atomicMax(&best[c1], k01 > k23 ? k01 : k23);
    }
}

// Kernel 3: single block — reduce partials, decode best keys, emit outputs.
__global__ void hough_out(const int* __restrict__ best,
                          const int* __restrict__ cnt,
                          const int* __restrict__ pcnt,
                          const float* __restrict__ pdz,
                          const float* __restrict__ extents,
                          const float* __restrict__ meta,
                          float* __restrict__ out) {
    const int tid = threadIdx.x;
    float* top_box    = out;          // 12 x 7
    float* top_pose   = out + 84;     // 12 x 7
    float* top_target = out + 168;    // 12 x 52
    float* top_weight = out + 792;    // 12 x 52
    float* top_domain = out + 1416;   // 12

    for (int j = tid; j < 624; j += 256) top_target[j] = 0.f;
    if (tid >= 244) top_domain[tid - 244] = 0.f;

    if (tid < CM1) {
        const int c1 = tid, c = tid + 1;
        int nl = 0; float ds = 0.f;
        #pragma unroll
        for (int b = 0; b < NBLK; ++b) {
            nl += pcnt[c1 * NBLK + b];
            ds += pdz [c1 * NBLK + b];
        }
        const int key = best[c1];
        const float vmax = (float)(key >> 15);
        const int bi = 19199 - (key & 32767);
        const float cx = (float)(bi % WW);
        const float cy = (float)(bi / WW);
        const float msum = fmaxf((float)nl, 1.0f);
        float z = expf(ds / msum);
        z = fmaxf(z, 1e-3f);
        const float fx = meta[0], fy = meta[4], pxc = meta[2], pyc = meta[5];
        const float bw = extents[c * 3 + 0] * fx / z;
        const float bh = extents[c * 3 + 1] * fy / z;
        const float nsamp = fmaxf((float)cnt[c1], 1.0f);
        const bool valid = (vmax >= 10.0f) && (nl >= 500) &&
                           (vmax >= 0.02f * nsamp);

        float* bx = top_box + c1 * 7;
        bx[0] = 0.0f;
        bx[1] = (float)c;
        bx[2] = cx - bw * 0.5f;
        bx[3] = cy - bh * 0.5f;
        bx[4] = cx + bw * 0.5f;
        bx[5] = cy + bh * 0.5f;
        bx[6] = vmax;

        const float tx = (cx - pxc) * z / fx;
        const float ty = (cy - pyc) * z / fy;
        float* ps = top_pose + c1 * 7;
        ps[0] = 1.f; ps[1] = 0.f; ps[2] = 0.f; ps[3] = 0.f;
        ps[4] = tx;  ps[5] = ty;  ps[6] = z;

        float* wt = top_weight + c1 * 52;
        const float wv = valid ? 1.0f : 0.0f;
        for (int j = 0; j < 52; ++j)
            wt[j] = ((j >> 2) == c) ? wv : 0.0f;
    }
}

extern "C" void kernel_launch(void* const* d_in, const int* in_sizes, int n_in,
                              void* d_out, int out_size, void* d_ws, size_t ws_size,
                              hipStream_t stream) {
    const int*   labels  = (const int*)d_in[0];
    const int*   masks   = (const int*)d_in[1];
    const float* vp      = (const float*)d_in[2];
    const float* extents = (const float*)d_in[3];
    const float* meta    = (const float*)d_in[5];
    float* out = (float*)d_out;

    char* ws = (char*)d_ws;
    float4* plist = (float4*)(ws + 0);
    int*    pcnt  = (int*)   (ws + 230400);
    float*  pdz   = (float*) (ws + 234000);
    int*    cnt   = (int*)   (ws + 237600);
    int*    best  = (int*)   (ws + 237648);

    hipMemsetAsync(ws + 237600, 0, 96, stream);   // cnt + best
    hough_prep<<<dim3(NBLK), dim3(256), 0, stream>>>(labels, masks, vp,
                                                     plist, cnt, pcnt, pdz);
    hough_vote<<<dim3(NBLK, CM1), dim3(256), 0, stream>>>(plist, cnt, best);
    hough_out<<<dim3(1), dim3(256), 0, stream>>>(best, cnt, pcnt, pdz,
                                                 extents, meta, out);
}

// Round 3
// 37.125 us; speedup vs baseline: 2.0295x; 1.1575x over previous
//
#include <hip/hip_runtime.h>
#include <hip/hip_bf16.h>

#define NCLS 13
#define HH 120
#define WW 160
#define HWSZ (HH * WW)       // 19200
#define PSAMP 1200           // 19200 / 16
#define CM1 (NCLS - 1)       // 12
#define NBLK 75              // HWSZ / 256

// ---------------- workspace layout (bytes) ----------------
// praw:  float4[12][75][16] @ 0        (230400 B)  ragged per-block lists
// bcnt:  int   [12][75]     @ 230400   (3600 B)    per-block sampled counts
// pcnt:  int   [12][75]     @ 234000   (3600 B)    per-block num_label partials
// pdz:   float [12][75]     @ 237600   (3600 B)    per-block dz-sum partials
// best:  int   [12]         @ 241200   (48 B)      packed argmax keys
// total 241248 B — no pre-initialization required (best zeroed in prep).

// Kernel 1: one thread per pixel. Per-block ragged compaction (LDS atomics
// only) + per-block per-class (count, dz-sum) partials via shfl trees.
__global__ void hough_prep(const int* __restrict__ labels,
                           const int* __restrict__ masks,
                           const float* __restrict__ vp,
                           float4* __restrict__ praw,
                           int* __restrict__ bcnt,
                           int* __restrict__ pcnt,
                           float* __restrict__ pdz,
                           int* __restrict__ best) {
    const int tid = threadIdx.x;
    const int b = blockIdx.x;
    const int i = b * 256 + tid;                   // < 19200 exactly
    __shared__ int lcnt[CM1];
    if (tid < CM1) lcnt[tid] = 0;
    if (b == 0 && tid >= 64 && tid < 64 + CM1) best[tid - 64] = 0;  // vote runs later
    __syncthreads();

    const int lab = labels[i];
    const bool valid = (lab > 0) && (masks[i] > 0);
    const int cls = valid ? lab - 1 : -1;
    float dz = 0.f;
    if (valid) dz = vp[(3 * lab + 2) * HWSZ + i];

    // sampled compaction into this block's ragged slots (order irrelevant)
    if (valid && ((tid & 15) == 0)) {
        float dx = vp[(3 * lab + 0) * HWSZ + i];
        float dy = vp[(3 * lab + 1) * HWSZ + i];
        float dn = __fadd_rn(
            __fsqrt_rn(__fadd_rn(__fmul_rn(dx, dx), __fmul_rn(dy, dy))), 1e-6f);
        int k = atomicAdd(&lcnt[cls], 1);          // LDS atomic, <16/block
        praw[(cls * NBLK + b) * 16 + k] =
            make_float4((float)(i % WW), (float)(i / WW),
                        __fdiv_rn(dx, dn), __fdiv_rn(dy, dn));
    }

    // per-wave per-class reductions (fixed shuffle tree -> deterministic)
    __shared__ float s_dz[4][CM1];
    __shared__ int   s_ct[4][CM1];
    const int w = tid >> 6, lane = tid & 63;
    for (int c1 = 0; c1 < CM1; ++c1) {
        unsigned long long bl = __ballot(cls == c1);
        float v = (cls == c1) ? dz : 0.f;
        for (int off = 32; off > 0; off >>= 1) v += __shfl_xor(v, off);
        if (lane == 0) { s_ct[w][c1] = (int)__popcll(bl); s_dz[w][c1] = v; }
    }
    __syncthreads();
    if (tid < CM1) {
        bcnt[tid * NBLK + b] = lcnt[tid];
        pcnt[tid * NBLK + b] = s_ct[0][tid] + s_ct[1][tid] + s_ct[2][tid] + s_ct[3][tid];
        pdz [tid * NBLK + b] = ((s_dz[0][tid] + s_dz[1][tid]) + s_dz[2][tid]) + s_dz[3][tid];
    }
}

// Kernel 2: densify ragged lists in LDS, vote, fused argmax via atomicMax.
// key = (v << 15) | (19199 - g): max v wins, ties -> smallest g.
__global__ void hough_vote(const float4* __restrict__ praw,
                           const int* __restrict__ bcnt,
                           int* __restrict__ best) {
    const int c1 = blockIdx.y;                       // 0..11
    const int g  = blockIdx.x * 256 + threadIdx.x;   // 0..19199
    __shared__ float4 s[PSAMP];
    __shared__ int scnt[NBLK];
    __shared__ int soff[NBLK + 1];
    if (threadIdx.x < NBLK) scnt[threadIdx.x] = bcnt[c1 * NBLK + threadIdx.x];
    __syncthreads();
    if (threadIdx.x == 0) {
        int acc = 0;
        for (int b2 = 0; b2 < NBLK; ++b2) { soff[b2] = acc; acc += scnt[b2]; }
        soff[NBLK] = acc;
    }
    __syncthreads();
    for (int t = threadIdx.x; t < NBLK * 16; t += 256) {
        const int b2 = t >> 4, k = t & 15;
        if (k < scnt[b2]) s[soff[b2] + k] = praw[(c1 * NBLK + b2) * 16 + k];
    }
    const int n = soff[NBLK];
    __syncthreads();

    const float xg = (float)(g % WW);
    const float yg = (float)(g / WW);
    int v = 0;
    for (int j = 0; j < n; ++j) {
        float4 e = s[j];
        float ddx = __fsub_rn(xg, e.x);
        float ddy = __fsub_rn(yg, e.y);
        float d2  = __fadd_rn(__fmul_rn(ddx, ddx), __fmul_rn(ddy, ddy));
        float dist = __fsqrt_rn(d2);
        float t2 = __fadd_rn(__fmul_rn(ddx, e.z), __fmul_rn(ddy, e.w));
        float cosang = __fdiv_rn(t2, fmaxf(dist, 1e-6f));
        v += (cosang > 0.9f && dist > 0.0f) ? 1 : 0;
    }

    int key = (v << 15) | (19199 - g);
    for (int off = 32; off > 0; off >>= 1) {
        int o = __shfl_xor(key, off);
        key = key > o ? key : o;
    }
    __shared__ int wmax[4];
    if ((threadIdx.x & 63) == 0) wmax[threadIdx.x >> 6] = key;
    __syncthreads();
    if (threadIdx.x == 0) {
        int k01 = wmax[0] > wmax[1] ? wmax[0] : wmax[1];
        int k23 = wmax[2] > wmax[3] ? wmax[2] : wmax[3];
        atomicMax(&best[c1], k01 > k23 ? k01 : k23);
    }
}

// Kernel 3: single block — reduce partials, decode best keys, emit outputs.
__global__ void hough_out(const int* __restrict__ best,
                          const int* __restrict__ bcnt,
                          const int* __restrict__ pcnt,
                          const float* __restrict__ pdz,
                          const float* __restrict__ extents,
                          const float* __restrict__ meta,
                          float* __restrict__ out) {
    const int tid = threadIdx.x;
    float* top_box    = out;          // 12 x 7
    float* top_pose   = out + 84;     // 12 x 7
    float* top_target = out + 168;    // 12 x 52
    float* top_weight = out + 792;    // 12 x 52
    float* top_domain = out + 1416;   // 12

    for (int j = tid; j < 624; j += 256) top_target[j] = 0.f;
    if (tid >= 244) top_domain[tid - 244] = 0.f;

    if (tid < CM1) {
        const int c1 = tid, c = tid + 1;
        int nl = 0, ns = 0; float ds = 0.f;
        #pragma unroll
        for (int b = 0; b < NBLK; ++b) {
            nl += pcnt[c1 * NBLK + b];
            ns += bcnt[c1 * NBLK + b];
            ds += pdz [c1 * NBLK + b];
        }
        const int key = best[c1];
        const float vmax = (float)(key >> 15);
        const int bi = 19199 - (key & 32767);
        const float cx = (float)(bi % WW);
        const float cy = (float)(bi / WW);
        const float msum = fmaxf((float)nl, 1.0f);
        float z = expf(ds / msum);
        z = fmaxf(z, 1e-3f);
        const float fx = meta[0], fy = meta[4], pxc = meta[2], pyc = meta[5];
        const float bw = extents[c * 3 + 0] * fx / z;
        const float bh = extents[c * 3 + 1] * fy / z;
        const float nsamp = fmaxf((float)ns, 1.0f);
        const bool valid = (vmax >= 10.0f) && (nl >= 500) &&
                           (vmax >= 0.02f * nsamp);

        float* bx = top_box + c1 * 7;
        bx[0] = 0.0f;
        bx[1] = (float)c;
        bx[2] = cx - bw * 0.5f;
        bx[3] = cy - bh * 0.5f;
        bx[4] = cx + bw * 0.5f;
        bx[5] = cy + bh * 0.5f;
        bx[6] = vmax;

        const float tx = (cx - pxc) * z / fx;
        const float ty = (cy - pyc) * z / fy;
        float* ps = top_pose + c1 * 7;
        ps[0] = 1.f; ps[1] = 0.f; ps[2] = 0.f; ps[3] = 0.f;
        ps[4] = tx;  ps[5] = ty;  ps[6] = z;

        float* wt = top_weight + c1 * 52;
        const float wv = valid ? 1.0f : 0.0f;
        for (int j = 0; j < 52; ++j)
            wt[j] = ((j >> 2) == c) ? wv : 0.0f;
    }
}

extern "C" void kernel_launch(void* const* d_in, const int* in_sizes, int n_in,
                              void* d_out, int out_size, void* d_ws, size_t ws_size,
                              hipStream_t stream) {
    const int*   labels  = (const int*)d_in[0];
    const int*   masks   = (const int*)d_in[1];
    const float* vp      = (const float*)d_in[2];
    const float* extents = (const float*)d_in[3];
    const float* meta    = (const float*)d_in[5];
    float* out = (float*)d_out;

    char* ws = (char*)d_ws;
    float4* praw = (float4*)(ws + 0);
    int*    bcnt = (int*)   (ws + 230400);
    int*    pcnt = (int*)   (ws + 234000);
    float*  pdz  = (float*) (ws + 237600);
    int*    best = (int*)   (ws + 241200);

    hough_prep<<<dim3(NBLK), dim3(256), 0, stream>>>(labels, masks, vp,
                                                     praw, bcnt, pcnt, pdz, best);
    hough_vote<<<dim3(NBLK, CM1), dim3(256), 0, stream>>>(praw, bcnt, best);
    hough_out<<<dim3(1), dim3(256), 0, stream>>>(best, bcnt, pcnt, pdz,
                                                 extents, meta, out);
}